// Round 1
// baseline (439.061 us; speedup 1.0000x reference)
//
#include <hip/hip_runtime.h>

// Problem constants (fixed by setup_inputs): B=8, C=19, H=512, W=1024
#define NCLASS 19
#define HW (512 * 1024)          // 2^19 pixels per (b, c) plane
#define NB 8
#define NPIX (NB * HW)           // 4,194,304 pixels
#define NGROUP (NPIX / 4)        // float4 groups

// Workspace layout: [pred_count[19] | true_count[19] | inter[19]] as uint32
// (zeroed via hipMemsetAsync each launch).

__global__ __launch_bounds__(256) void iou_count_kernel(
    const float* __restrict__ preds,
    const int* __restrict__ targets,
    unsigned int* __restrict__ g_pred,
    unsigned int* __restrict__ g_true,
    unsigned int* __restrict__ g_inter)
{
    __shared__ unsigned int s_pred[NCLASS];
    __shared__ unsigned int s_true[NCLASS];
    __shared__ unsigned int s_inter[NCLASS];

    const int t = threadIdx.x;
    if (t < NCLASS) { s_pred[t] = 0u; s_true[t] = 0u; s_inter[t] = 0u; }
    __syncthreads();

    const int stride = gridDim.x * blockDim.x;
    const int4* __restrict__ tgt4 = (const int4*)targets;

    for (int g = blockIdx.x * blockDim.x + t; g < NGROUP; g += stride) {
        const int p0 = g << 2;                 // first pixel of this group of 4
        const int b  = p0 >> 19;               // HW == 2^19
        const int hw = p0 & (HW - 1);          // multiple of 4 -> 16B aligned

        // base of this batch's class-0 plane at pixel hw, viewed as float4
        const float4* __restrict__ base =
            (const float4*)(preds + (size_t)b * NCLASS * HW + hw);
        const size_t plane4 = HW / 4;          // plane stride in float4 units

        float4 m = base[0];
        int ix = 0, iy = 0, iz = 0, iw = 0;
        #pragma unroll
        for (int c = 1; c < NCLASS; ++c) {
            float4 v = base[(size_t)c * plane4];
            if (v.x > m.x) { m.x = v.x; ix = c; }
            if (v.y > m.y) { m.y = v.y; iy = c; }
            if (v.z > m.z) { m.z = v.z; iz = c; }
            if (v.w > m.w) { m.w = v.w; iw = c; }
        }

        const int4 tg = tgt4[g];

        atomicAdd(&s_pred[ix], 1u);
        atomicAdd(&s_pred[iy], 1u);
        atomicAdd(&s_pred[iz], 1u);
        atomicAdd(&s_pred[iw], 1u);

        atomicAdd(&s_true[tg.x], 1u);
        atomicAdd(&s_true[tg.y], 1u);
        atomicAdd(&s_true[tg.z], 1u);
        atomicAdd(&s_true[tg.w], 1u);

        if (ix == tg.x) atomicAdd(&s_inter[ix], 1u);
        if (iy == tg.y) atomicAdd(&s_inter[iy], 1u);
        if (iz == tg.z) atomicAdd(&s_inter[iz], 1u);
        if (iw == tg.w) atomicAdd(&s_inter[iw], 1u);
    }

    __syncthreads();
    if (t < NCLASS) {
        if (s_pred[t])  atomicAdd(&g_pred[t],  s_pred[t]);
        if (s_true[t])  atomicAdd(&g_true[t],  s_true[t]);
        if (s_inter[t]) atomicAdd(&g_inter[t], s_inter[t]);
    }
}

__global__ void iou_finalize_kernel(
    const unsigned int* __restrict__ g_pred,
    const unsigned int* __restrict__ g_true,
    const unsigned int* __restrict__ g_inter,
    float* __restrict__ out)
{
    __shared__ float s_iou[NCLASS];
    const int t = threadIdx.x;
    if (t < NCLASS) {
        const unsigned int pc = g_pred[t];
        const unsigned int tc = g_true[t];
        const unsigned int ic = g_inter[t];
        const unsigned int un = pc + tc - ic;
        const unsigned int und = un > 1u ? un : 1u;
        const float iou = (tc > 0u) ? ((float)ic / (float)und) : 0.0f;
        s_iou[t] = iou;
        if (t >= 1) out[t - 1] = iou;   // iou = iou_all[1:]
    }
    __syncthreads();
    if (t == 0) {
        float s = 0.0f;
        for (int c = 1; c < NCLASS; ++c) s += s_iou[c];
        out[NCLASS - 1] = s / (float)(NCLASS - 1);  // mean_iou at out[18]
    }
}

extern "C" void kernel_launch(void* const* d_in, const int* in_sizes, int n_in,
                              void* d_out, int out_size, void* d_ws, size_t ws_size,
                              hipStream_t stream) {
    const float* preds  = (const float*)d_in[0];
    const int* targets  = (const int*)d_in[1];
    float* out          = (float*)d_out;

    unsigned int* g_pred  = (unsigned int*)d_ws;
    unsigned int* g_true  = g_pred + NCLASS;
    unsigned int* g_inter = g_true + NCLASS;

    // Zero the 3x19 counters (d_ws is re-poisoned to 0xAA before every call).
    hipMemsetAsync(d_ws, 0, 3 * NCLASS * sizeof(unsigned int), stream);

    const int block = 256;
    const int grid  = 2048;   // 8 blocks/CU worth of grid-stride coverage
    iou_count_kernel<<<grid, block, 0, stream>>>(preds, targets,
                                                 g_pred, g_true, g_inter);
    iou_finalize_kernel<<<1, 64, 0, stream>>>(g_pred, g_true, g_inter, out);
}

// Round 2
// 433.292 us; speedup vs baseline: 1.0133x; 1.0133x over previous
//
#include <hip/hip_runtime.h>

// Problem constants (fixed by setup_inputs): B=8, C=19, H=512, W=1024
#define NCLASS 19
#define HW (512 * 1024)          // 2^19 pixels per (b, c) plane
#define NB 8
#define NPIX (NB * HW)           // 4,194,304 pixels
#define NGROUP (NPIX / 4)        // 1,048,576 float4 groups
#define GROUPS_PER_BLOCK 512     // 2048 px per block; divides HW/4 -> plane-aligned
#define GRID (NGROUP / GROUPS_PER_BLOCK)   // 2048 blocks

typedef float v4f __attribute__((ext_vector_type(4)));
typedef int   v4i __attribute__((ext_vector_type(4)));

// Workspace layout: [pred_count[19] | true_count[19] | inter[19]] as uint32
// (zeroed via hipMemsetAsync each launch).

__global__ __launch_bounds__(256) void iou_count_kernel(
    const float* __restrict__ preds,
    const int* __restrict__ targets,
    unsigned int* __restrict__ g_pred,
    unsigned int* __restrict__ g_true,
    unsigned int* __restrict__ g_inter)
{
    __shared__ unsigned int s_pred[NCLASS];
    __shared__ unsigned int s_true[NCLASS];
    __shared__ unsigned int s_inter[NCLASS];

    const int t = threadIdx.x;
    if (t < NCLASS) { s_pred[t] = 0u; s_true[t] = 0u; s_inter[t] = 0u; }
    __syncthreads();

    // Block handles 512 consecutive float4 groups (2048 pixels), all within
    // one batch's plane (512 divides HW/4 = 131072). Lane handles group
    // gblk+t and gblk+t+256 -> every dwordx4 is a contiguous 1KB wave access.
    const int gblk = blockIdx.x * GROUPS_PER_BLOCK;
    const int p0   = gblk << 2;              // first pixel of block
    const int b    = p0 >> 19;               // HW == 2^19
    const int hw   = p0 & (HW - 1);

    const v4f* __restrict__ base =
        (const v4f*)(preds + (size_t)b * NCLASS * HW + hw) + t;
    const size_t plane4 = HW / 4;            // plane stride in float4 units

    v4f m0 = __builtin_nontemporal_load(&base[0]);
    v4f m1 = __builtin_nontemporal_load(&base[256]);
    int i0x = 0, i0y = 0, i0z = 0, i0w = 0;
    int i1x = 0, i1y = 0, i1z = 0, i1w = 0;

    #pragma unroll
    for (int c = 1; c < NCLASS; ++c) {
        const v4f a = __builtin_nontemporal_load(&base[(size_t)c * plane4]);
        const v4f d = __builtin_nontemporal_load(&base[(size_t)c * plane4 + 256]);
        if (a.x > m0.x) { m0.x = a.x; i0x = c; }
        if (a.y > m0.y) { m0.y = a.y; i0y = c; }
        if (a.z > m0.z) { m0.z = a.z; i0z = c; }
        if (a.w > m0.w) { m0.w = a.w; i0w = c; }
        if (d.x > m1.x) { m1.x = d.x; i1x = c; }
        if (d.y > m1.y) { m1.y = d.y; i1y = c; }
        if (d.z > m1.z) { m1.z = d.z; i1z = c; }
        if (d.w > m1.w) { m1.w = d.w; i1w = c; }
    }

    const v4i* __restrict__ tgt4 = (const v4i*)targets + gblk + t;
    const v4i ta = __builtin_nontemporal_load(&tgt4[0]);
    const v4i tb = __builtin_nontemporal_load(&tgt4[256]);

    atomicAdd(&s_pred[i0x], 1u);
    atomicAdd(&s_pred[i0y], 1u);
    atomicAdd(&s_pred[i0z], 1u);
    atomicAdd(&s_pred[i0w], 1u);
    atomicAdd(&s_pred[i1x], 1u);
    atomicAdd(&s_pred[i1y], 1u);
    atomicAdd(&s_pred[i1z], 1u);
    atomicAdd(&s_pred[i1w], 1u);

    atomicAdd(&s_true[ta.x], 1u);
    atomicAdd(&s_true[ta.y], 1u);
    atomicAdd(&s_true[ta.z], 1u);
    atomicAdd(&s_true[ta.w], 1u);
    atomicAdd(&s_true[tb.x], 1u);
    atomicAdd(&s_true[tb.y], 1u);
    atomicAdd(&s_true[tb.z], 1u);
    atomicAdd(&s_true[tb.w], 1u);

    if (i0x == ta.x) atomicAdd(&s_inter[i0x], 1u);
    if (i0y == ta.y) atomicAdd(&s_inter[i0y], 1u);
    if (i0z == ta.z) atomicAdd(&s_inter[i0z], 1u);
    if (i0w == ta.w) atomicAdd(&s_inter[i0w], 1u);
    if (i1x == tb.x) atomicAdd(&s_inter[i1x], 1u);
    if (i1y == tb.y) atomicAdd(&s_inter[i1y], 1u);
    if (i1z == tb.z) atomicAdd(&s_inter[i1z], 1u);
    if (i1w == tb.w) atomicAdd(&s_inter[i1w], 1u);

    __syncthreads();
    if (t < NCLASS) {
        if (s_pred[t])  atomicAdd(&g_pred[t],  s_pred[t]);
        if (s_true[t])  atomicAdd(&g_true[t],  s_true[t]);
        if (s_inter[t]) atomicAdd(&g_inter[t], s_inter[t]);
    }
}

__global__ void iou_finalize_kernel(
    const unsigned int* __restrict__ g_pred,
    const unsigned int* __restrict__ g_true,
    const unsigned int* __restrict__ g_inter,
    float* __restrict__ out)
{
    __shared__ float s_iou[NCLASS];
    const int t = threadIdx.x;
    if (t < NCLASS) {
        const unsigned int pc = g_pred[t];
        const unsigned int tc = g_true[t];
        const unsigned int ic = g_inter[t];
        const unsigned int un = pc + tc - ic;
        const unsigned int und = un > 1u ? un : 1u;
        const float iou = (tc > 0u) ? ((float)ic / (float)und) : 0.0f;
        s_iou[t] = iou;
        if (t >= 1) out[t - 1] = iou;   // iou = iou_all[1:]
    }
    __syncthreads();
    if (t == 0) {
        float s = 0.0f;
        for (int c = 1; c < NCLASS; ++c) s += s_iou[c];
        out[NCLASS - 1] = s / (float)(NCLASS - 1);  // mean_iou at out[18]
    }
}

extern "C" void kernel_launch(void* const* d_in, const int* in_sizes, int n_in,
                              void* d_out, int out_size, void* d_ws, size_t ws_size,
                              hipStream_t stream) {
    const float* preds  = (const float*)d_in[0];
    const int* targets  = (const int*)d_in[1];
    float* out          = (float*)d_out;

    unsigned int* g_pred  = (unsigned int*)d_ws;
    unsigned int* g_true  = g_pred + NCLASS;
    unsigned int* g_inter = g_true + NCLASS;

    // Zero the 3x19 counters (d_ws is re-poisoned to 0xAA before every call).
    hipMemsetAsync(d_ws, 0, 3 * NCLASS * sizeof(unsigned int), stream);

    iou_count_kernel<<<GRID, 256, 0, stream>>>(preds, targets,
                                               g_pred, g_true, g_inter);
    iou_finalize_kernel<<<1, 64, 0, stream>>>(g_pred, g_true, g_inter, out);
}

// Round 3
// 403.596 us; speedup vs baseline: 1.0879x; 1.0736x over previous
//
#include <hip/hip_runtime.h>

// Problem constants (fixed by setup_inputs): B=8, C=19, H=512, W=1024
#define NCLASS 19
#define NCNT   (3 * NCLASS)      // 57 counters: pred[19] | true[19] | inter[19]
#define HW (512 * 1024)          // 2^19 pixels per (b, c) plane
#define NB 8
#define NPIX (NB * HW)           // 4,194,304 pixels
#define NGROUP (NPIX / 4)        // 1,048,576 float4 groups
#define GROUPS_PER_BLOCK 512     // 2048 px per block; divides HW/4 -> plane-aligned
#define GRID (NGROUP / GROUPS_PER_BLOCK)   // 2048 blocks

typedef float v4f __attribute__((ext_vector_type(4)));
typedef int   v4i __attribute__((ext_vector_type(4)));
typedef unsigned int v4u __attribute__((ext_vector_type(4)));

// Workspace: partials[NCNT][GRID] uint32 (counter-major). Every slot is
// written unconditionally by its block -> no zero-init / memset node needed.

__global__ __launch_bounds__(256) void iou_count_kernel(
    const float* __restrict__ preds,
    const int* __restrict__ targets,
    unsigned int* __restrict__ partials)
{
    __shared__ unsigned int s_cnt[NCNT];   // pred | true | inter

    const int t = threadIdx.x;
    if (t < NCNT) s_cnt[t] = 0u;
    __syncthreads();

    // Block handles 512 consecutive float4 groups (2048 pixels), all within
    // one batch's plane (512 divides HW/4 = 131072). Lane handles group
    // gblk+t and gblk+t+256 -> every dwordx4 is a contiguous 1KB wave access.
    const int gblk = blockIdx.x * GROUPS_PER_BLOCK;
    const int p0   = gblk << 2;              // first pixel of block
    const int b    = p0 >> 19;               // HW == 2^19
    const int hw   = p0 & (HW - 1);

    const v4f* __restrict__ base =
        (const v4f*)(preds + (size_t)b * NCLASS * HW + hw) + t;
    const size_t plane4 = HW / 4;            // plane stride in float4 units

    v4f m0 = __builtin_nontemporal_load(&base[0]);
    v4f m1 = __builtin_nontemporal_load(&base[256]);
    int i0x = 0, i0y = 0, i0z = 0, i0w = 0;
    int i1x = 0, i1y = 0, i1z = 0, i1w = 0;

    #pragma unroll
    for (int c = 1; c < NCLASS; ++c) {
        const v4f a = __builtin_nontemporal_load(&base[(size_t)c * plane4]);
        const v4f d = __builtin_nontemporal_load(&base[(size_t)c * plane4 + 256]);
        if (a.x > m0.x) { m0.x = a.x; i0x = c; }
        if (a.y > m0.y) { m0.y = a.y; i0y = c; }
        if (a.z > m0.z) { m0.z = a.z; i0z = c; }
        if (a.w > m0.w) { m0.w = a.w; i0w = c; }
        if (d.x > m1.x) { m1.x = d.x; i1x = c; }
        if (d.y > m1.y) { m1.y = d.y; i1y = c; }
        if (d.z > m1.z) { m1.z = d.z; i1z = c; }
        if (d.w > m1.w) { m1.w = d.w; i1w = c; }
    }

    const v4i* __restrict__ tgt4 = (const v4i*)targets + gblk + t;
    const v4i ta = __builtin_nontemporal_load(&tgt4[0]);
    const v4i tb = __builtin_nontemporal_load(&tgt4[256]);

    atomicAdd(&s_cnt[i0x], 1u);
    atomicAdd(&s_cnt[i0y], 1u);
    atomicAdd(&s_cnt[i0z], 1u);
    atomicAdd(&s_cnt[i0w], 1u);
    atomicAdd(&s_cnt[i1x], 1u);
    atomicAdd(&s_cnt[i1y], 1u);
    atomicAdd(&s_cnt[i1z], 1u);
    atomicAdd(&s_cnt[i1w], 1u);

    atomicAdd(&s_cnt[NCLASS + ta.x], 1u);
    atomicAdd(&s_cnt[NCLASS + ta.y], 1u);
    atomicAdd(&s_cnt[NCLASS + ta.z], 1u);
    atomicAdd(&s_cnt[NCLASS + ta.w], 1u);
    atomicAdd(&s_cnt[NCLASS + tb.x], 1u);
    atomicAdd(&s_cnt[NCLASS + tb.y], 1u);
    atomicAdd(&s_cnt[NCLASS + tb.z], 1u);
    atomicAdd(&s_cnt[NCLASS + tb.w], 1u);

    if (i0x == ta.x) atomicAdd(&s_cnt[2 * NCLASS + i0x], 1u);
    if (i0y == ta.y) atomicAdd(&s_cnt[2 * NCLASS + i0y], 1u);
    if (i0z == ta.z) atomicAdd(&s_cnt[2 * NCLASS + i0z], 1u);
    if (i0w == ta.w) atomicAdd(&s_cnt[2 * NCLASS + i0w], 1u);
    if (i1x == tb.x) atomicAdd(&s_cnt[2 * NCLASS + i1x], 1u);
    if (i1y == tb.y) atomicAdd(&s_cnt[2 * NCLASS + i1y], 1u);
    if (i1z == tb.z) atomicAdd(&s_cnt[2 * NCLASS + i1z], 1u);
    if (i1w == tb.w) atomicAdd(&s_cnt[2 * NCLASS + i1w], 1u);

    __syncthreads();
    // Counter-major layout: partials[j*GRID + bid]. For fixed j, consecutive
    // blocks write consecutive dwords -> L2 write-combines across blocks.
    if (t < NCNT) partials[t * GRID + blockIdx.x] = s_cnt[t];
}

__global__ __launch_bounds__(1024) void iou_finalize_kernel(
    const unsigned int* __restrict__ partials,
    float* __restrict__ out)
{
    // 16 threads per counter, each reads uint4 -> 64 entries per iter,
    // 32 iters cover GRID=2048 entries. Coalesced 256B per 16-lane group.
    __shared__ unsigned int s_red[NCNT][16];
    __shared__ unsigned int s_tot[NCNT];
    __shared__ float s_iou[NCLASS];

    const int t = threadIdx.x;
    const int j = t >> 4;          // counter index, valid for j < 57
    const int k = t & 15;

    if (j < NCNT) {
        const v4u* __restrict__ p4 = (const v4u*)(partials + j * GRID);
        unsigned int s = 0;
        #pragma unroll
        for (int i = 0; i < 32; ++i) {
            const v4u v = p4[i * 16 + k];
            s += v.x + v.y + v.z + v.w;
        }
        s_red[j][k] = s;
    }
    __syncthreads();
    if (j < NCNT && k == 0) {
        unsigned int s = 0;
        #pragma unroll
        for (int i = 0; i < 16; ++i) s += s_red[j][i];
        s_tot[j] = s;
    }
    __syncthreads();

    if (t < NCLASS) {
        const unsigned int pc = s_tot[t];
        const unsigned int tc = s_tot[NCLASS + t];
        const unsigned int ic = s_tot[2 * NCLASS + t];
        const unsigned int un = pc + tc - ic;
        const unsigned int und = un > 1u ? un : 1u;
        const float iou = (tc > 0u) ? ((float)ic / (float)und) : 0.0f;
        s_iou[t] = iou;
        if (t >= 1) out[t - 1] = iou;   // iou = iou_all[1:]
    }
    __syncthreads();
    if (t == 0) {
        float s = 0.0f;
        for (int c = 1; c < NCLASS; ++c) s += s_iou[c];
        out[NCLASS - 1] = s / (float)(NCLASS - 1);  // mean_iou at out[18]
    }
}

extern "C" void kernel_launch(void* const* d_in, const int* in_sizes, int n_in,
                              void* d_out, int out_size, void* d_ws, size_t ws_size,
                              hipStream_t stream) {
    const float* preds  = (const float*)d_in[0];
    const int* targets  = (const int*)d_in[1];
    float* out          = (float*)d_out;
    unsigned int* partials = (unsigned int*)d_ws;   // NCNT*GRID*4 = 467 KB

    iou_count_kernel<<<GRID, 256, 0, stream>>>(preds, targets, partials);
    iou_finalize_kernel<<<1, 1024, 0, stream>>>(partials, out);
}